// Round 12
// baseline (351.213 us; speedup 1.0000x reference)
//
#include <hip/hip_runtime.h>
#include <hip/hip_bf16.h>
#include <math.h>

#define H 64
#define H2 128
#define EPS_MSG 1e-7f
#define LN_EPS 1e-5f
#define LOG2E 1.4426950408889634f
#define LN2 0.6931471805599453f
#define YSTR 136         // mlp LDS node-row stride in shorts (272B, 16B-aligned)
#define BSTRIDE 4608     // bdata per-bucket stride (ints); bucket mean 3072, +28 sigma
#define OSTRIDE 5376     // srcs_sorted per-bucket stride (BSTRIDE + 768 pad slack)
#define CHUNK 8192       // edges per block in bscat

typedef __attribute__((ext_vector_type(8))) short bf16x8;
typedef __attribute__((ext_vector_type(4))) float f32x4;

__device__ __forceinline__ unsigned short f2bf(float f) {
    union { float f; unsigned int i; } x; x.f = f;
    unsigned int r = x.i + 0x7FFF + ((x.i >> 16) & 1);   // RNE
    return (unsigned short)(r >> 16);
}

// ================= bucketed CSR build (2 kernels, fixed-stride buckets) =================
__global__ __launch_bounds__(256) void bscat_k(const int* __restrict__ src,
                                               const int* __restrict__ dst,
                                               int* __restrict__ bcnt,
                                               unsigned int* __restrict__ bdata,
                                               int E, int nbuck) {
    __shared__ int h[512], base[512];
    for (int i = threadIdx.x; i < nbuck; i += 256) h[i] = 0;
    __syncthreads();
    int lo = blockIdx.x * CHUNK;
    int hi = lo + CHUNK; if (hi > E) hi = E;
    for (int i = lo + threadIdx.x; i < hi; i += 256)
        atomicAdd(&h[dst[i] >> 8], 1);
    __syncthreads();
    for (int i = threadIdx.x; i < nbuck; i += 256) {
        int c = h[i];
        base[i] = c ? atomicAdd(&bcnt[i], c) : 0;
        h[i] = 0;
    }
    __syncthreads();
    for (int i = lo + threadIdx.x; i < hi; i += 256) {
        int d = dst[i];
        int b = d >> 8;
        int pos = base[b] + atomicAdd(&h[b], 1);
        bdata[(size_t)b * BSTRIDE + pos] = ((unsigned int)src[i] << 8) | (unsigned int)(d & 255);
    }
}

// per bucket: stage, per-node counts, pad each node's list to x4 with sentinel Nn.
// rowq[node] = {beg (srcs index), quad count}; zeroed for padded tail nodes.
__global__ __launch_bounds__(256) void bsort_k(const unsigned int* __restrict__ bdata,
                                               const int* __restrict__ bcnt,
                                               int2* __restrict__ rowq,
                                               int* __restrict__ srcs_sorted,
                                               int Nn) {
    __shared__ unsigned int stage[BSTRIDE];
    __shared__ int cnt[256], pre[256], ex[256];
    int b = blockIdx.x, tid = threadIdx.x;
    int m = bcnt[b]; if (m > BSTRIDE) m = BSTRIDE;
    size_t lo = (size_t)b * BSTRIDE;
    int oLo = b * OSTRIDE;
    for (int i = tid; i < m; i += 256) stage[i] = bdata[lo + i];
    cnt[tid] = 0;
    __syncthreads();
    for (int i = tid; i < m; i += 256) atomicAdd(&cnt[stage[i] & 255], 1);
    __syncthreads();
    int myc = cnt[tid];
    int pc = (myc + 3) & ~3;
    pre[tid] = pc;
    __syncthreads();
    #pragma unroll
    for (int off = 1; off < 256; off <<= 1) {
        int t = (tid >= off) ? pre[tid - off] : 0;
        __syncthreads();
        pre[tid] += t;
        __syncthreads();
    }
    int pexcl = pre[tid] - pc;
    ex[tid] = pexcl;
    int node = (b << 8) + tid;
    if (node < Nn) rowq[node] = make_int2(oLo + pexcl, pc >> 2);
    else           rowq[node] = make_int2(0, 0);
    for (int p = myc; p < pc; ++p) srcs_sorted[oLo + pexcl + p] = Nn;
    __syncthreads();
    cnt[tid] = 0;
    __syncthreads();
    for (int i = tid; i < m; i += 256) {
        unsigned int v = stage[i];
        int dl = v & 255;
        int p = ex[dl] + atomicAdd(&cnt[dl], 1);
        srcs_sorted[oLo + p] = (int)(v >> 8);
    }
}

// ---------------- weight prep (Wf1 k-rows permuted to match channel layout) ----------------
__global__ void wprep_k(const float* __restrict__ W1, const float* __restrict__ W2,
                        unsigned short* __restrict__ Wf1, unsigned short* __restrict__ Wf2) {
    int idx = blockIdx.x * 256 + threadIdx.x;
    const int half = 3 * 8192;
    if (idx < half) {
        int layer = idx / 8192, rem = idx - layer * 8192;
        int t = rem >> 9;
        int l = (rem >> 3) & 63;
        int i = rem & 7;
        int h = t >> 3, ct = t & 7;
        int kpos = h * 32 + (l >> 4) * 8 + i;
        int k = (kpos & 3) * 16 + (kpos >> 2);    // true channel at stored position kpos
        int j = ct * 16 + (l & 15);
        Wf1[idx] = f2bf(W1[(size_t)layer * H * H2 + (size_t)k * H2 + j]);
    } else if (idx < 2 * half) {
        int id2 = idx - half;
        int layer = id2 / 8192, rem = id2 - layer * 8192;
        int t = rem >> 9;
        int l = (rem >> 3) & 63;
        int i = rem & 7;
        int kk = t >> 2, ct2 = t & 3;
        int k = kk * 32 + (l >> 4) * 8 + i;
        int j = ct2 * 16 + (l & 15);
        Wf2[id2] = f2bf(W2[(size_t)layer * H2 * H + (size_t)k * H + j]);
    }
}

// ---------------- encoder: permuted Zself/Zmsg; sentinel row Nn in Zmsg ----------------
__global__ void encoder_k(const float* __restrict__ x, const float* __restrict__ W,
                          const float* __restrict__ b,
                          unsigned short* __restrict__ Zself, unsigned short* __restrict__ Zmsg,
                          const float* __restrict__ t, int Nn) {
    int idx = blockIdx.x * blockDim.x + threadIdx.x;
    if (idx >= (Nn + 1) * H) return;
    int n = idx >> 6, c = idx & 63;
    if (n == Nn) { Zmsg[idx] = f2bf(-200.f); return; }
    float acc = b[c];
    #pragma unroll
    for (int k = 0; k < 3; ++k) acc = fmaf(x[n * 3 + k], W[k * H + c], acc);
    int j = (c & 15) * 4 + (c >> 4);
    Zself[(size_t)n * H + j] = f2bf(acc);
    Zmsg[(size_t)n * H + j]  = f2bf(fmaxf(acc, 0.f) * (LOG2E) * t[0]);
}

// ---------------- gather: 4 nodes per wave, deep prologue, mask-free padded lists ----------------
__global__ __launch_bounds__(256) void gather_k(
    const unsigned short* __restrict__ Zmsg, const unsigned short* __restrict__ Zself,
    unsigned short* __restrict__ Gbf,
    const int2* __restrict__ rowq,
    const int* __restrict__ srcs,
    const float* __restrict__ t, int layer, int Nn)
{
    int wid = threadIdx.x >> 6, lane = threadIdx.x & 63;
    int nA = (blockIdx.x * 4 + wid) * 4;
    if (nA >= Nn) return;
    int slot = lane >> 4;
    int ch4  = lane & 15;
    float scale = (LN2) * __builtin_amdgcn_rcpf(t[layer]);

    int4 rAB = *(const int4*)&rowq[nA];       // begA,qA,begB,qB
    int4 rCD = *(const int4*)&rowq[nA + 2];   // begC,qC,begD,qD
    int begA = rAB.x, qA = rAB.y, begB = rAB.z, qB = rAB.w;
    int begC = rCD.x, qC = rCD.y, begD = rCD.z, qD = rCD.w;

    // self row: slot s loads node nA+s (clamped); one instruction covers 4 rows
    int ns = nA + slot; if (ns >= Nn) ns = Nn - 1;
    const unsigned short* selfTab = (layer == 0) ? Zself : Zmsg;
    uint2 sv = *(const uint2*)(selfTab + (size_t)ns * H + ch4 * 4);

    #define LQ(qq, beg, i)                                                     \
        {                                                                      \
            int s = srcs[(beg) + 4 * (i) + slot];                              \
            qq = *(const uint2*)(Zmsg + (size_t)s * H + ch4 * 4);              \
        }

    // prologue: up to 16 loads in flight before first use
    uint2 a0={0,0},a1={0,0},a2={0,0},a3={0,0};
    uint2 b0={0,0},b1={0,0},b2={0,0},b3={0,0};
    uint2 c0={0,0},c1={0,0},c2={0,0},c3={0,0};
    uint2 e0={0,0},e1={0,0},e2={0,0},e3={0,0};
    if (qA > 0) LQ(a0, begA, 0)
    if (qB > 0) LQ(b0, begB, 0)
    if (qC > 0) LQ(c0, begC, 0)
    if (qD > 0) LQ(e0, begD, 0)
    if (qA > 1) LQ(a1, begA, 1)
    if (qB > 1) LQ(b1, begB, 1)
    if (qC > 1) LQ(c1, begC, 1)
    if (qD > 1) LQ(e1, begD, 1)
    if (qA > 2) LQ(a2, begA, 2)
    if (qB > 2) LQ(b2, begB, 2)
    if (qC > 2) LQ(c2, begC, 2)
    if (qD > 2) LQ(e2, begD, 2)
    if (qA > 3) LQ(a3, begA, 3)
    if (qB > 3) LQ(b3, begB, 3)
    if (qC > 3) LQ(c3, begC, 3)
    if (qD > 3) LQ(e3, begD, 3)

    float dA0=0.f,dA1=0.f,dA2=0.f,dA3=0.f,sA0=0.f,sA1=0.f,sA2=0.f,sA3=0.f;
    float dB0=0.f,dB1=0.f,dB2=0.f,dB3=0.f,sB0=0.f,sB1=0.f,sB2=0.f,sB3=0.f;
    float dC0=0.f,dC1=0.f,dC2=0.f,dC3=0.f,sC0=0.f,sC1=0.f,sC2=0.f,sC3=0.f;
    float dD0=0.f,dD1=0.f,dD2=0.f,dD3=0.f,sD0=0.f,sD1=0.f,sD2=0.f,sD3=0.f;

    #define PROC(qq, dd0,dd1,dd2,dd3, ss0,ss1,ss2,ss3)                         \
        {                                                                      \
            float u0 = __uint_as_float(qq.x << 16);                            \
            float u1 = __uint_as_float(qq.x & 0xffff0000u);                    \
            float u2 = __uint_as_float(qq.y << 16);                            \
            float u3 = __uint_as_float(qq.y & 0xffff0000u);                    \
            float w0 = __builtin_amdgcn_exp2f(u0);                             \
            float w1 = __builtin_amdgcn_exp2f(u1);                             \
            float w2 = __builtin_amdgcn_exp2f(u2);                             \
            float w3 = __builtin_amdgcn_exp2f(u3);                             \
            dd0 += w0; dd1 += w1; dd2 += w2; dd3 += w3;                        \
            ss0 = fmaf(u0, w0, ss0); ss1 = fmaf(u1, w1, ss1);                  \
            ss2 = fmaf(u2, w2, ss2); ss3 = fmaf(u3, w3, ss3);                  \
        }
    #define PROCA(qq) PROC(qq, dA0,dA1,dA2,dA3, sA0,sA1,sA2,sA3)
    #define PROCB(qq) PROC(qq, dB0,dB1,dB2,dB3, sB0,sB1,sB2,sB3)
    #define PROCC(qq) PROC(qq, dC0,dC1,dC2,dC3, sC0,sC1,sC2,sC3)
    #define PROCD(qq) PROC(qq, dD0,dD1,dD2,dD3, sD0,sD1,sD2,sD3)

    if (qA > 0) {
        int i = 0;
        #pragma unroll 1
        for (; i + 4 < qA; i += 4) {
            PROCA(a0) LQ(a0, begA, i + 4)
            PROCA(a1) if (i + 5 < qA) LQ(a1, begA, i + 5)
            PROCA(a2) if (i + 6 < qA) LQ(a2, begA, i + 6)
            PROCA(a3) if (i + 7 < qA) LQ(a3, begA, i + 7)
        }
        PROCA(a0)
        if (i + 1 < qA) PROCA(a1)
        if (i + 2 < qA) PROCA(a2)
        if (i + 3 < qA) PROCA(a3)
    }
    if (qB > 0) {
        int i = 0;
        #pragma unroll 1
        for (; i + 4 < qB; i += 4) {
            PROCB(b0) LQ(b0, begB, i + 4)
            PROCB(b1) if (i + 5 < qB) LQ(b1, begB, i + 5)
            PROCB(b2) if (i + 6 < qB) LQ(b2, begB, i + 6)
            PROCB(b3) if (i + 7 < qB) LQ(b3, begB, i + 7)
        }
        PROCB(b0)
        if (i + 1 < qB) PROCB(b1)
        if (i + 2 < qB) PROCB(b2)
        if (i + 3 < qB) PROCB(b3)
    }
    if (qC > 0) {
        int i = 0;
        #pragma unroll 1
        for (; i + 4 < qC; i += 4) {
            PROCC(c0) LQ(c0, begC, i + 4)
            PROCC(c1) if (i + 5 < qC) LQ(c1, begC, i + 5)
            PROCC(c2) if (i + 6 < qC) LQ(c2, begC, i + 6)
            PROCC(c3) if (i + 7 < qC) LQ(c3, begC, i + 7)
        }
        PROCC(c0)
        if (i + 1 < qC) PROCC(c1)
        if (i + 2 < qC) PROCC(c2)
        if (i + 3 < qC) PROCC(c3)
    }
    if (qD > 0) {
        int i = 0;
        #pragma unroll 1
        for (; i + 4 < qD; i += 4) {
            PROCD(e0) LQ(e0, begD, i + 4)
            PROCD(e1) if (i + 5 < qD) LQ(e1, begD, i + 5)
            PROCD(e2) if (i + 6 < qD) LQ(e2, begD, i + 6)
            PROCD(e3) if (i + 7 < qD) LQ(e3, begD, i + 7)
        }
        PROCD(e0)
        if (i + 1 < qD) PROCD(e1)
        if (i + 2 < qD) PROCD(e2)
        if (i + 3 < qD) PROCD(e3)
    }
    #undef LQ
    #undef PROC
    #undef PROCA
    #undef PROCB
    #undef PROCC
    #undef PROCD

    // reduce across the 4 slot groups (all lanes end with totals for all 4 nodes)
    #pragma unroll
    for (int o = 16; o <= 32; o <<= 1) {
        dA0 += __shfl_xor(dA0, o, 64); dA1 += __shfl_xor(dA1, o, 64);
        dA2 += __shfl_xor(dA2, o, 64); dA3 += __shfl_xor(dA3, o, 64);
        sA0 += __shfl_xor(sA0, o, 64); sA1 += __shfl_xor(sA1, o, 64);
        sA2 += __shfl_xor(sA2, o, 64); sA3 += __shfl_xor(sA3, o, 64);
        dB0 += __shfl_xor(dB0, o, 64); dB1 += __shfl_xor(dB1, o, 64);
        dB2 += __shfl_xor(dB2, o, 64); dB3 += __shfl_xor(dB3, o, 64);
        sB0 += __shfl_xor(sB0, o, 64); sB1 += __shfl_xor(sB1, o, 64);
        sB2 += __shfl_xor(sB2, o, 64); sB3 += __shfl_xor(sB3, o, 64);
        dC0 += __shfl_xor(dC0, o, 64); dC1 += __shfl_xor(dC1, o, 64);
        dC2 += __shfl_xor(dC2, o, 64); dC3 += __shfl_xor(dC3, o, 64);
        sC0 += __shfl_xor(sC0, o, 64); sC1 += __shfl_xor(sC1, o, 64);
        sC2 += __shfl_xor(sC2, o, 64); sC3 += __shfl_xor(sC3, o, 64);
        dD0 += __shfl_xor(dD0, o, 64); dD1 += __shfl_xor(dD1, o, 64);
        dD2 += __shfl_xor(dD2, o, 64); dD3 += __shfl_xor(dD3, o, 64);
        sD0 += __shfl_xor(sD0, o, 64); sD1 += __shfl_xor(sD1, o, 64);
        sD2 += __shfl_xor(sD2, o, 64); sD3 += __shfl_xor(sD3, o, 64);
    }

    // slot-select: lane (slot s) finalizes node nA+s
    #define SEL(vA, vB, vC, vD) ((slot & 2) ? ((slot & 1) ? (vD) : (vC)) : ((slot & 1) ? (vB) : (vA)))
    float ds0 = SEL(dA0, dB0, dC0, dD0), ds1 = SEL(dA1, dB1, dC1, dD1);
    float ds2 = SEL(dA2, dB2, dC2, dD2), ds3 = SEL(dA3, dB3, dC3, dD3);
    float ss0 = SEL(sA0, sB0, sC0, sD0), ss1 = SEL(sA1, sB1, sC1, sD1);
    float ss2 = SEL(sA2, sB2, sC2, sD2), ss3 = SEL(sA3, sB3, sC3, sD3);
    int   qn  = SEL(qA, qB, qC, qD);
    #undef SEL

    float o0 = __uint_as_float(sv.x << 16);
    float o1 = __uint_as_float(sv.x & 0xffff0000u);
    float o2 = __uint_as_float(sv.y << 16);
    float o3 = __uint_as_float(sv.y & 0xffff0000u);
    if (layer != 0) { o0 *= scale; o1 *= scale; o2 *= scale; o3 *= scale; }
    float t0 = fmaf(ss0 * __builtin_amdgcn_rcpf(ds0), scale, EPS_MSG);
    float t1 = fmaf(ss1 * __builtin_amdgcn_rcpf(ds1), scale, EPS_MSG);
    float t2 = fmaf(ss2 * __builtin_amdgcn_rcpf(ds2), scale, EPS_MSG);
    float t3 = fmaf(ss3 * __builtin_amdgcn_rcpf(ds3), scale, EPS_MSG);
    o0 += (qn > 0) ? t0 : 0.f;
    o1 += (qn > 0) ? t1 : 0.f;
    o2 += (qn > 0) ? t2 : 0.f;
    o3 += (qn > 0) ? t3 : 0.f;

    uint2 pv;
    pv.x = (unsigned int)f2bf(o0) | ((unsigned int)f2bf(o1) << 16);
    pv.y = (unsigned int)f2bf(o2) | ((unsigned int)f2bf(o3) << 16);
    if (nA + slot < Nn)
        *(uint2*)(Gbf + (size_t)(nA + slot) * H + ch4 * 4) = pv;
}

// ---------------- mlp (MFMA) + fused prenorm (mode 0) / final (mode 1) ----------------
__global__ __launch_bounds__(256) void mlp_k(
    const unsigned short* __restrict__ Gbf, float* __restrict__ B,
    const unsigned short* __restrict__ Wf1, const unsigned short* __restrict__ Wf2,
    const float* __restrict__ b1, const float* __restrict__ g,
    const float* __restrict__ beta, const float* __restrict__ b2,
    unsigned short* __restrict__ Zmsg,
    const float* __restrict__ tptr, const float* __restrict__ ln_g,
    const float* __restrict__ ln_b, const float* __restrict__ lin_W,
    const float* __restrict__ lin_b, float* __restrict__ outp,
    int wlayer, int lnidx, int resid, int mode, int Nn)
{
    __shared__ __align__(16) unsigned short yt[4][16 * YSTR];
    int wid = threadIdx.x >> 6, lane = threadIdx.x & 63;
    int gq = lane >> 4, c = lane & 15;
    int n0 = (blockIdx.x * 4 + wid) * 16;

    Wf1 += (size_t)wlayer * 8192; Wf2 += (size_t)wlayer * 8192;
    b1 += wlayer * H2; g += wlayer * H2; beta += wlayer * H2; b2 += wlayer * H;

    int nA = n0 + c; if (nA >= Nn) nA = Nn - 1;
    bf16x8 a0 = *(const bf16x8*)(Gbf + (size_t)nA * H + gq * 8);
    bf16x8 a1 = *(const bf16x8*)(Gbf + (size_t)nA * H + 32 + gq * 8);

    f32x4 acc[8];
    #pragma unroll
    for (int ct = 0; ct < 8; ++ct) {
        f32x4 z = {0.f, 0.f, 0.f, 0.f};
        bf16x8 w0 = *(const bf16x8*)(Wf1 + (size_t)(ct * 64 + lane) * 8);
        bf16x8 w1 = *(const bf16x8*)(Wf1 + (size_t)((8 + ct) * 64 + lane) * 8);
        z = __builtin_amdgcn_mfma_f32_16x16x32_bf16(a0, w0, z, 0, 0, 0);
        z = __builtin_amdgcn_mfma_f32_16x16x32_bf16(a1, w1, z, 0, 0, 0);
        acc[ct] = z;
    }

    float v[8][4];
    #pragma unroll
    for (int ct = 0; ct < 8; ++ct) {
        float bias = b1[ct * 16 + c];
        #pragma unroll
        for (int r = 0; r < 4; ++r) v[ct][r] = acc[ct][r] + bias;
    }
    float mean[4], inv[4];
    #pragma unroll
    for (int r = 0; r < 4; ++r) {
        float s = 0.f;
        #pragma unroll
        for (int ct = 0; ct < 8; ++ct) s += v[ct][r];
        #pragma unroll
        for (int o = 1; o < 16; o <<= 1) s += __shfl_xor(s, o, 64);
        mean[r] = s * (1.f / H2);
    }
    #pragma unroll
    for (int r = 0; r < 4; ++r) {
        float s = 0.f;
        #pragma unroll
        for (int ct = 0; ct < 8; ++ct) { float d = v[ct][r] - mean[r]; s = fmaf(d, d, s); }
        #pragma unroll
        for (int o = 1; o < 16; o <<= 1) s += __shfl_xor(s, o, 64);
        inv[r] = rsqrtf(s * (1.f / H2) + LN_EPS);
    }
    unsigned short* Y = yt[wid];
    #pragma unroll
    for (int ct = 0; ct < 8; ++ct) {
        float gg = g[ct * 16 + c], bb = beta[ct * 16 + c];
        #pragma unroll
        for (int r = 0; r < 4; ++r) {
            float yv = fmaxf(fmaf((v[ct][r] - mean[r]) * inv[r], gg, bb), 0.f);
            Y[(gq * 4 + r) * YSTR + ct * 16 + c] = f2bf(yv);
        }
    }

    f32x4 acc2[4];
    #pragma unroll
    for (int t = 0; t < 4; ++t) acc2[t] = (f32x4){0.f, 0.f, 0.f, 0.f};
    #pragma unroll
    for (int kk = 0; kk < 4; ++kk) {
        bf16x8 af = *(const bf16x8*)(Y + c * YSTR + kk * 32 + gq * 8);
        #pragma unroll
        for (int t = 0; t < 4; ++t) {
            bf16x8 wf = *(const bf16x8*)(Wf2 + (size_t)((kk * 4 + t) * 64 + lane) * 8);
            acc2[t] = __builtin_amdgcn_mfma_f32_16x16x32_bf16(af, wf, acc2[t], 0, 0, 0);
        }
    }

    float b2v[4], gg2[4], bb2[4], lw[4][3];
    const float* g64 = ln_g + lnidx * H;
    const float* be64 = ln_b + lnidx * H;
    #pragma unroll
    for (int tt = 0; tt < 4; ++tt) {
        b2v[tt] = b2[tt * 16 + c];
        gg2[tt] = g64[tt * 16 + c];
        bb2[tt] = be64[tt * 16 + c];
    }
    if (mode == 1) {
        #pragma unroll
        for (int tt = 0; tt < 4; ++tt)
            #pragma unroll
            for (int k = 0; k < 3; ++k) lw[tt][k] = lin_W[(tt * 16 + c) * 3 + k];
    }
    float kmsg = (mode == 0) ? (LOG2E * tptr[lnidx]) : 0.f;

    #pragma unroll
    for (int r = 0; r < 4; ++r) {
        int n = n0 + gq * 4 + r;
        int nc = (n < Nn) ? n : (Nn - 1);
        float hv[4];
        #pragma unroll
        for (int tt = 0; tt < 4; ++tt) hv[tt] = acc2[tt][r] + b2v[tt];
        if (resid) {
            float4 old = *(const float4*)&B[(size_t)nc * H + c * 4];
            hv[0] += old.x; hv[1] += old.y; hv[2] += old.z; hv[3] += old.w;
        }
        float s = hv[0] + hv[1] + hv[2] + hv[3];
        #pragma unroll
        for (int o = 1; o < 16; o <<= 1) s += __shfl_xor(s, o, 64);
        float mu = s * (1.f / H);
        float q = 0.f;
        #pragma unroll
        for (int tt = 0; tt < 4; ++tt) { float d = hv[tt] - mu; q = fmaf(d, d, q); }
        #pragma unroll
        for (int o = 1; o < 16; o <<= 1) q += __shfl_xor(q, o, 64);
        float iv = rsqrtf(q * (1.f / H) + LN_EPS);
        float z[4];
        #pragma unroll
        for (int tt = 0; tt < 4; ++tt)
            z[tt] = fmaxf(fmaf((hv[tt] - mu) * iv, gg2[tt], bb2[tt]), 0.f);

        if (mode == 0) {
            if (n < Nn) {
                float4 hq = {hv[0], hv[1], hv[2], hv[3]};
                *(float4*)&B[(size_t)n * H + c * 4] = hq;
                uint2 zm;
                zm.x = (unsigned int)f2bf(z[0] * kmsg) | ((unsigned int)f2bf(z[1] * kmsg) << 16);
                zm.y = (unsigned int)f2bf(z[2] * kmsg) | ((unsigned int)f2bf(z[3] * kmsg) << 16);
                *(uint2*)&Zmsg[(size_t)n * H + c * 4] = zm;
            }
        } else {
            float p0 = 0.f, p1 = 0.f, p2 = 0.f;
            #pragma unroll
            for (int tt = 0; tt < 4; ++tt) {
                p0 = fmaf(z[tt], lw[tt][0], p0);
                p1 = fmaf(z[tt], lw[tt][1], p1);
                p2 = fmaf(z[tt], lw[tt][2], p2);
            }
            #pragma unroll
            for (int o = 1; o < 16; o <<= 1) {
                p0 += __shfl_xor(p0, o, 64);
                p1 += __shfl_xor(p1, o, 64);
                p2 += __shfl_xor(p2, o, 64);
            }
            if (c == 0 && n < Nn) {
                outp[(size_t)n * 3 + 0] = p0 + lin_b[0];
                outp[(size_t)n * 3 + 1] = p1 + lin_b[1];
                outp[(size_t)n * 3 + 2] = p2 + lin_b[2];
            }
        }
    }
}

extern "C" void kernel_launch(void* const* d_in, const int* in_sizes, int n_in,
                              void* d_out, int out_size, void* d_ws, size_t ws_size,
                              hipStream_t stream) {
    const float* x        = (const float*)d_in[0];
    const int*   eidx     = (const int*)  d_in[1];
    const float* enc_W    = (const float*)d_in[2];
    const float* enc_b    = (const float*)d_in[3];
    const float* t        = (const float*)d_in[4];
    const float* mlp_W1   = (const float*)d_in[5];
    const float* mlp_b1   = (const float*)d_in[6];
    const float* mlp_g    = (const float*)d_in[7];
    const float* mlp_beta = (const float*)d_in[8];
    const float* mlp_W2   = (const float*)d_in[9];
    const float* mlp_b2   = (const float*)d_in[10];
    const float* ln_g     = (const float*)d_in[11];
    const float* ln_b     = (const float*)d_in[12];
    const float* lin_W    = (const float*)d_in[13];
    const float* lin_b    = (const float*)d_in[14];
    float* out = (float*)d_out;

    const int N = in_sizes[0] / 3;
    const int E = in_sizes[1] / 2;
    const int* src = eidx;
    const int* dst = eidx + E;
    const int nbuck = (N + 255) >> 8;

    // workspace layout (~77 MB peak; bdata aliases Gbf — consumed by bsort before gather)
    float* Bm = (float*)d_ws;                          // N*64 f32
    int2* rowq = (int2*)(Bm + (size_t)N * H);          // 512*256 int2 (covers padded tail)
    int* bcnt      = (int*)(rowq + 512 * 256);         // 512
    int* srcs_sorted = bcnt + 512;                     // 512*OSTRIDE
    unsigned short* Zself = (unsigned short*)(srcs_sorted + 512 * OSTRIDE); // N*64
    unsigned short* Zmsg  = Zself + (size_t)N * H;                // (N+1)*64
    unsigned short* Gbf   = Zmsg + (size_t)(N + 1) * H;           // N*64
    unsigned short* Wf1   = Gbf + (size_t)N * H;                  // 3*8192
    unsigned short* Wf2   = Wf1 + 3 * 8192;                       // 3*8192
    unsigned int* bdata = (unsigned int*)Gbf;          // 512*BSTRIDE u32 (9.4MB <= 12.8MB)

    const int eBlocks = (E + CHUNK - 1) / CHUNK;

    hipMemsetAsync(bcnt, 0, 512 * sizeof(int), stream);
    bscat_k<<<eBlocks, 256, 0, stream>>>(src, dst, bcnt, bdata, E, nbuck);
    bsort_k<<<nbuck, 256, 0, stream>>>(bdata, bcnt, rowq, srcs_sorted, N);

    wprep_k<<<192, 256, 0, stream>>>(mlp_W1, mlp_W2, Wf1, Wf2);
    encoder_k<<<((size_t)(N + 1) * H + 255) / 256, 256, 0, stream>>>(x, enc_W, enc_b, Zself, Zmsg, t, N);

    const int gBlocks   = (N + 15) / 16;    // gather: 4 nodes/wave, 4 waves/block
    const int mlpBlocks = (N + 63) / 64;    // mlp: 16 nodes/wave

    gather_k<<<gBlocks, 256, 0, stream>>>(Zmsg, Zself, Gbf, rowq, srcs_sorted, t, 0, N);
    mlp_k<<<mlpBlocks, 256, 0, stream>>>(Gbf, Bm, Wf1, Wf2, mlp_b1, mlp_g, mlp_beta, mlp_b2,
                                         Zmsg, t, ln_g, ln_b, lin_W, lin_b, out,
                                         0, 1, 0, 0, N);
    gather_k<<<gBlocks, 256, 0, stream>>>(Zmsg, Zself, Gbf, rowq, srcs_sorted, t, 1, N);
    mlp_k<<<mlpBlocks, 256, 0, stream>>>(Gbf, Bm, Wf1, Wf2, mlp_b1, mlp_g, mlp_beta, mlp_b2,
                                         Zmsg, t, ln_g, ln_b, lin_W, lin_b, out,
                                         1, 2, 1, 0, N);
    gather_k<<<gBlocks, 256, 0, stream>>>(Zmsg, Zself, Gbf, rowq, srcs_sorted, t, 2, N);
    mlp_k<<<mlpBlocks, 256, 0, stream>>>(Gbf, Bm, Wf1, Wf2, mlp_b1, mlp_g, mlp_beta, mlp_b2,
                                         Zmsg, t, ln_g, ln_b, lin_W, lin_b, out,
                                         2, 0, 1, 1, N);
}

// Round 13
// 339.256 us; speedup vs baseline: 1.0352x; 1.0352x over previous
//
#include <hip/hip_runtime.h>
#include <hip/hip_bf16.h>
#include <math.h>

#define H 64
#define H2 128
#define EPS_MSG 1e-7f
#define LN_EPS 1e-5f
#define LOG2E 1.4426950408889634f
#define LN2 0.6931471805599453f
#define YSTR 136         // mlp LDS node-row stride in shorts (272B, 16B-aligned)
#define BSTRIDE 4608     // bdata per-bucket stride (ints); bucket mean 3072, +28 sigma
#define OSTRIDE 6144     // srcs_sorted per-bucket stride (group-max padded; mean ~4500, +21 sigma)
#define CHUNK 8192       // edges per block in bscat

typedef __attribute__((ext_vector_type(8))) short bf16x8;
typedef __attribute__((ext_vector_type(4))) float f32x4;

__device__ __forceinline__ unsigned short f2bf(float f) {
    union { float f; unsigned int i; } x; x.f = f;
    unsigned int r = x.i + 0x7FFF + ((x.i >> 16) & 1);   // RNE
    return (unsigned short)(r >> 16);
}

// ================= bucketed CSR build (2 kernels, fixed-stride buckets) =================
__global__ __launch_bounds__(256) void bscat_k(const int* __restrict__ src,
                                               const int* __restrict__ dst,
                                               int* __restrict__ bcnt,
                                               unsigned int* __restrict__ bdata,
                                               int E, int nbuck) {
    __shared__ int h[512], base[512];
    for (int i = threadIdx.x; i < nbuck; i += 256) h[i] = 0;
    __syncthreads();
    int lo = blockIdx.x * CHUNK;
    int hi = lo + CHUNK; if (hi > E) hi = E;
    for (int i = lo + threadIdx.x; i < hi; i += 256)
        atomicAdd(&h[dst[i] >> 8], 1);
    __syncthreads();
    for (int i = threadIdx.x; i < nbuck; i += 256) {
        int c = h[i];
        base[i] = c ? atomicAdd(&bcnt[i], c) : 0;
        h[i] = 0;
    }
    __syncthreads();
    for (int i = lo + threadIdx.x; i < hi; i += 256) {
        int d = dst[i];
        int b = d >> 8;
        int pos = base[b] + atomicAdd(&h[b], 1);
        bdata[(size_t)b * BSTRIDE + pos] = ((unsigned int)src[i] << 8) | (unsigned int)(d & 255);
    }
}

// per bucket: stage, per-node counts, pad every aligned group of 4 nodes to the
// GROUP MAX slot count with sentinel Nn (uniform loop count in gather).
// rowq[node] = {beg | (deg>0), group quad count}.
__global__ __launch_bounds__(256) void bsort_k(const unsigned int* __restrict__ bdata,
                                               const int* __restrict__ bcnt,
                                               int2* __restrict__ rowq,
                                               int* __restrict__ srcs_sorted,
                                               int Nn) {
    __shared__ unsigned int stage[BSTRIDE];
    __shared__ int cnt[256], pre[256], ex[256], pc4[256];
    int b = blockIdx.x, tid = threadIdx.x;
    int m = bcnt[b]; if (m > BSTRIDE) m = BSTRIDE;
    size_t lo = (size_t)b * BSTRIDE;
    int oLo = b * OSTRIDE;
    for (int i = tid; i < m; i += 256) stage[i] = bdata[lo + i];
    cnt[tid] = 0;
    __syncthreads();
    for (int i = tid; i < m; i += 256) atomicAdd(&cnt[stage[i] & 255], 1);
    __syncthreads();
    int myc = cnt[tid];
    int pc = (myc + 3) & ~3;
    pc4[tid] = pc;
    __syncthreads();
    int g0 = tid & ~3;
    int gmax = max(max(pc4[g0], pc4[g0 + 1]), max(pc4[g0 + 2], pc4[g0 + 3]));
    pre[tid] = gmax;
    __syncthreads();
    #pragma unroll
    for (int off = 1; off < 256; off <<= 1) {
        int t = (tid >= off) ? pre[tid - off] : 0;
        __syncthreads();
        pre[tid] += t;
        __syncthreads();
    }
    int pexcl = pre[tid] - gmax;
    ex[tid] = pexcl;
    int node = (b << 8) + tid;
    if (node < Nn)
        rowq[node] = make_int2((oLo + pexcl) | (myc > 0 ? 1 : 0), gmax >> 2);
    // sentinel fill up to group-max capacity (bounded by OSTRIDE for safety)
    for (int p = myc; p < gmax; ++p) {
        int pos = pexcl + p;
        if (pos < OSTRIDE) srcs_sorted[oLo + pos] = Nn;
    }
    __syncthreads();
    cnt[tid] = 0;
    __syncthreads();
    for (int i = tid; i < m; i += 256) {
        unsigned int v = stage[i];
        int dl = v & 255;
        int p = ex[dl] + atomicAdd(&cnt[dl], 1);
        if (p < OSTRIDE) srcs_sorted[oLo + p] = (int)(v >> 8);
    }
}

// ---------------- weight prep (Wf1 k-rows permuted to match channel layout) ----------------
__global__ void wprep_k(const float* __restrict__ W1, const float* __restrict__ W2,
                        unsigned short* __restrict__ Wf1, unsigned short* __restrict__ Wf2) {
    int idx = blockIdx.x * 256 + threadIdx.x;
    const int half = 3 * 8192;
    if (idx < half) {
        int layer = idx / 8192, rem = idx - layer * 8192;
        int t = rem >> 9;
        int l = (rem >> 3) & 63;
        int i = rem & 7;
        int h = t >> 3, ct = t & 7;
        int kpos = h * 32 + (l >> 4) * 8 + i;
        int k = (kpos & 3) * 16 + (kpos >> 2);    // true channel at stored position kpos
        int j = ct * 16 + (l & 15);
        Wf1[idx] = f2bf(W1[(size_t)layer * H * H2 + (size_t)k * H2 + j]);
    } else if (idx < 2 * half) {
        int id2 = idx - half;
        int layer = id2 / 8192, rem = id2 - layer * 8192;
        int t = rem >> 9;
        int l = (rem >> 3) & 63;
        int i = rem & 7;
        int kk = t >> 2, ct2 = t & 3;
        int k = kk * 32 + (l >> 4) * 8 + i;
        int j = ct2 * 16 + (l & 15);
        Wf2[id2] = f2bf(W2[(size_t)layer * H2 * H + (size_t)k * H + j]);
    }
}

// ---------------- encoder: permuted Zself/Zmsg; sentinel row Nn in Zmsg ----------------
__global__ void encoder_k(const float* __restrict__ x, const float* __restrict__ W,
                          const float* __restrict__ b,
                          unsigned short* __restrict__ Zself, unsigned short* __restrict__ Zmsg,
                          const float* __restrict__ t, int Nn) {
    int idx = blockIdx.x * blockDim.x + threadIdx.x;
    if (idx >= (Nn + 1) * H) return;
    int n = idx >> 6, c = idx & 63;
    if (n == Nn) { Zmsg[idx] = f2bf(-200.f); return; }
    float acc = b[c];
    #pragma unroll
    for (int k = 0; k < 3; ++k) acc = fmaf(x[n * 3 + k], W[k * H + c], acc);
    int j = (c & 15) * 4 + (c >> 4);
    Zself[(size_t)n * H + j] = f2bf(acc);
    Zmsg[(size_t)n * H + j]  = f2bf(fmaxf(acc, 0.f) * (LOG2E) * t[0]);
}

// ---------------- gather: 4 nodes/wave, round-robin interleave, uniform loop ----------------
__global__ __launch_bounds__(256) void gather_k(
    const unsigned short* __restrict__ Zmsg, const unsigned short* __restrict__ Zself,
    unsigned short* __restrict__ Gbf,
    const int2* __restrict__ rowq,
    const int* __restrict__ srcs,
    const float* __restrict__ t, int layer, int Nn)
{
    int wid = threadIdx.x >> 6, lane = threadIdx.x & 63;
    int nA = (blockIdx.x * 4 + wid) * 4;
    if (nA >= Nn) return;
    int slot = lane >> 4;
    int ch4  = lane & 15;
    float scale = (LN2) * __builtin_amdgcn_rcpf(t[layer]);

    int4 rAB = *(const int4*)&rowq[nA];       // begA|fA,q, begB|fB,q
    int4 rCD = *(const int4*)&rowq[nA + 2];   // begC|fC,q, begD|fD,q
    int begA = rAB.x & ~3, hasA = rAB.x & 1;
    int begB = rAB.z & ~3, hasB = rAB.z & 1;
    int begC = rCD.x & ~3, hasC = rCD.x & 1;
    int begD = rCD.z & ~3, hasD = rCD.z & 1;
    int q = rAB.y;                            // group-uniform quad count

    // self row: slot s loads node nA+s (clamped)
    int ns = nA + slot; if (ns >= Nn) ns = Nn - 1;
    const unsigned short* selfTab = (layer == 0) ? Zself : Zmsg;
    uint2 sv = *(const uint2*)(selfTab + (size_t)ns * H + ch4 * 4);

    #define LQ(qq, beg, i)                                                     \
        {                                                                      \
            int s = srcs[(beg) + 4 * (i) + slot];                              \
            qq = *(const uint2*)(Zmsg + (size_t)s * H + ch4 * 4);              \
        }

    uint2 a0={0,0},a1={0,0},a2={0,0},a3={0,0};
    uint2 b0={0,0},b1={0,0},b2={0,0},b3={0,0};
    uint2 c0={0,0},c1={0,0},c2={0,0},c3={0,0};
    uint2 e0={0,0},e1={0,0},e2={0,0},e3={0,0};

    float dA0=0.f,dA1=0.f,dA2=0.f,dA3=0.f,sA0=0.f,sA1=0.f,sA2=0.f,sA3=0.f;
    float dB0=0.f,dB1=0.f,dB2=0.f,dB3=0.f,sB0=0.f,sB1=0.f,sB2=0.f,sB3=0.f;
    float dC0=0.f,dC1=0.f,dC2=0.f,dC3=0.f,sC0=0.f,sC1=0.f,sC2=0.f,sC3=0.f;
    float dD0=0.f,dD1=0.f,dD2=0.f,dD3=0.f,sD0=0.f,sD1=0.f,sD2=0.f,sD3=0.f;

    #define PROC(qq, dd0,dd1,dd2,dd3, ss0,ss1,ss2,ss3)                         \
        {                                                                      \
            float u0 = __uint_as_float(qq.x << 16);                            \
            float u1 = __uint_as_float(qq.x & 0xffff0000u);                    \
            float u2 = __uint_as_float(qq.y << 16);                            \
            float u3 = __uint_as_float(qq.y & 0xffff0000u);                    \
            float w0 = __builtin_amdgcn_exp2f(u0);                             \
            float w1 = __builtin_amdgcn_exp2f(u1);                             \
            float w2 = __builtin_amdgcn_exp2f(u2);                             \
            float w3 = __builtin_amdgcn_exp2f(u3);                             \
            dd0 += w0; dd1 += w1; dd2 += w2; dd3 += w3;                        \
            ss0 = fmaf(u0, w0, ss0); ss1 = fmaf(u1, w1, ss1);                  \
            ss2 = fmaf(u2, w2, ss2); ss3 = fmaf(u3, w3, ss3);                  \
        }
    #define PROCA(qq) PROC(qq, dA0,dA1,dA2,dA3, sA0,sA1,sA2,sA3)
    #define PROCB(qq) PROC(qq, dB0,dB1,dB2,dB3, sB0,sB1,sB2,sB3)
    #define PROCC(qq) PROC(qq, dC0,dC1,dC2,dC3, sC0,sC1,sC2,sC3)
    #define PROCD(qq) PROC(qq, dD0,dD1,dD2,dD3, sD0,sD1,sD2,sD3)

    if (q > 0) {
        // prologue: 16 loads in flight, interleaved across nodes
        LQ(a0, begA, 0) LQ(b0, begB, 0) LQ(c0, begC, 0) LQ(e0, begD, 0)
        if (q > 1) { LQ(a1, begA, 1) LQ(b1, begB, 1) LQ(c1, begC, 1) LQ(e1, begD, 1) }
        if (q > 2) { LQ(a2, begA, 2) LQ(b2, begB, 2) LQ(c2, begC, 2) LQ(e2, begD, 2) }
        if (q > 3) { LQ(a3, begA, 3) LQ(b3, begB, 3) LQ(c3, begC, 3) LQ(e3, begD, 3) }

        int i = 0;
        #pragma unroll 1
        for (; i + 4 < q; i += 4) {   // steady state: 16 outstanding loads
            PROCA(a0) LQ(a0, begA, i + 4)
            PROCB(b0) LQ(b0, begB, i + 4)
            PROCC(c0) LQ(c0, begC, i + 4)
            PROCD(e0) LQ(e0, begD, i + 4)
            bool c5 = (i + 5 < q), c6 = (i + 6 < q), c7 = (i + 7 < q);
            PROCA(a1) if (c5) LQ(a1, begA, i + 5)
            PROCB(b1) if (c5) LQ(b1, begB, i + 5)
            PROCC(c1) if (c5) LQ(c1, begC, i + 5)
            PROCD(e1) if (c5) LQ(e1, begD, i + 5)
            PROCA(a2) if (c6) LQ(a2, begA, i + 6)
            PROCB(b2) if (c6) LQ(b2, begB, i + 6)
            PROCC(c2) if (c6) LQ(c2, begC, i + 6)
            PROCD(e2) if (c6) LQ(e2, begD, i + 6)
            PROCA(a3) if (c7) LQ(a3, begA, i + 7)
            PROCB(b3) if (c7) LQ(b3, begB, i + 7)
            PROCC(c3) if (c7) LQ(c3, begC, i + 7)
            PROCD(e3) if (c7) LQ(e3, begD, i + 7)
        }
        // tail: quads i..q-1 (uniform conditions)
        PROCA(a0) PROCB(b0) PROCC(c0) PROCD(e0)
        if (i + 1 < q) { PROCA(a1) PROCB(b1) PROCC(c1) PROCD(e1) }
        if (i + 2 < q) { PROCA(a2) PROCB(b2) PROCC(c2) PROCD(e2) }
        if (i + 3 < q) { PROCA(a3) PROCB(b3) PROCC(c3) PROCD(e3) }
    }
    #undef LQ
    #undef PROC
    #undef PROCA
    #undef PROCB
    #undef PROCC
    #undef PROCD

    // reduce across the 4 slot groups (all lanes end with totals for all 4 nodes)
    #pragma unroll
    for (int o = 16; o <= 32; o <<= 1) {
        dA0 += __shfl_xor(dA0, o, 64); dA1 += __shfl_xor(dA1, o, 64);
        dA2 += __shfl_xor(dA2, o, 64); dA3 += __shfl_xor(dA3, o, 64);
        sA0 += __shfl_xor(sA0, o, 64); sA1 += __shfl_xor(sA1, o, 64);
        sA2 += __shfl_xor(sA2, o, 64); sA3 += __shfl_xor(sA3, o, 64);
        dB0 += __shfl_xor(dB0, o, 64); dB1 += __shfl_xor(dB1, o, 64);
        dB2 += __shfl_xor(dB2, o, 64); dB3 += __shfl_xor(dB3, o, 64);
        sB0 += __shfl_xor(sB0, o, 64); sB1 += __shfl_xor(sB1, o, 64);
        sB2 += __shfl_xor(sB2, o, 64); sB3 += __shfl_xor(sB3, o, 64);
        dC0 += __shfl_xor(dC0, o, 64); dC1 += __shfl_xor(dC1, o, 64);
        dC2 += __shfl_xor(dC2, o, 64); dC3 += __shfl_xor(dC3, o, 64);
        sC0 += __shfl_xor(sC0, o, 64); sC1 += __shfl_xor(sC1, o, 64);
        sC2 += __shfl_xor(sC2, o, 64); sC3 += __shfl_xor(sC3, o, 64);
        dD0 += __shfl_xor(dD0, o, 64); dD1 += __shfl_xor(dD1, o, 64);
        dD2 += __shfl_xor(dD2, o, 64); dD3 += __shfl_xor(dD3, o, 64);
        sD0 += __shfl_xor(sD0, o, 64); sD1 += __shfl_xor(sD1, o, 64);
        sD2 += __shfl_xor(sD2, o, 64); sD3 += __shfl_xor(sD3, o, 64);
    }

    // slot-select: lane (slot s) finalizes node nA+s
    #define SEL(vA, vB, vC, vD) ((slot & 2) ? ((slot & 1) ? (vD) : (vC)) : ((slot & 1) ? (vB) : (vA)))
    float ds0 = SEL(dA0, dB0, dC0, dD0), ds1 = SEL(dA1, dB1, dC1, dD1);
    float ds2 = SEL(dA2, dB2, dC2, dD2), ds3 = SEL(dA3, dB3, dC3, dD3);
    float ss0 = SEL(sA0, sB0, sC0, sD0), ss1 = SEL(sA1, sB1, sC1, sD1);
    float ss2 = SEL(sA2, sB2, sC2, sD2), ss3 = SEL(sA3, sB3, sC3, sD3);
    int   hn  = SEL(hasA, hasB, hasC, hasD);
    #undef SEL

    float o0 = __uint_as_float(sv.x << 16);
    float o1 = __uint_as_float(sv.x & 0xffff0000u);
    float o2 = __uint_as_float(sv.y << 16);
    float o3 = __uint_as_float(sv.y & 0xffff0000u);
    if (layer != 0) { o0 *= scale; o1 *= scale; o2 *= scale; o3 *= scale; }
    float t0 = fmaf(ss0 * __builtin_amdgcn_rcpf(ds0), scale, EPS_MSG);
    float t1 = fmaf(ss1 * __builtin_amdgcn_rcpf(ds1), scale, EPS_MSG);
    float t2 = fmaf(ss2 * __builtin_amdgcn_rcpf(ds2), scale, EPS_MSG);
    float t3 = fmaf(ss3 * __builtin_amdgcn_rcpf(ds3), scale, EPS_MSG);
    o0 += hn ? t0 : 0.f;
    o1 += hn ? t1 : 0.f;
    o2 += hn ? t2 : 0.f;
    o3 += hn ? t3 : 0.f;

    uint2 pv;
    pv.x = (unsigned int)f2bf(o0) | ((unsigned int)f2bf(o1) << 16);
    pv.y = (unsigned int)f2bf(o2) | ((unsigned int)f2bf(o3) << 16);
    if (nA + slot < Nn)
        *(uint2*)(Gbf + (size_t)(nA + slot) * H + ch4 * 4) = pv;
}

// ---------------- mlp (MFMA) + fused prenorm (mode 0) / final (mode 1) ----------------
__global__ __launch_bounds__(256) void mlp_k(
    const unsigned short* __restrict__ Gbf, float* __restrict__ B,
    const unsigned short* __restrict__ Wf1, const unsigned short* __restrict__ Wf2,
    const float* __restrict__ b1, const float* __restrict__ g,
    const float* __restrict__ beta, const float* __restrict__ b2,
    unsigned short* __restrict__ Zmsg,
    const float* __restrict__ tptr, const float* __restrict__ ln_g,
    const float* __restrict__ ln_b, const float* __restrict__ lin_W,
    const float* __restrict__ lin_b, float* __restrict__ outp,
    int wlayer, int lnidx, int resid, int mode, int Nn)
{
    __shared__ __align__(16) unsigned short yt[4][16 * YSTR];
    int wid = threadIdx.x >> 6, lane = threadIdx.x & 63;
    int gq = lane >> 4, c = lane & 15;
    int n0 = (blockIdx.x * 4 + wid) * 16;

    Wf1 += (size_t)wlayer * 8192; Wf2 += (size_t)wlayer * 8192;
    b1 += wlayer * H2; g += wlayer * H2; beta += wlayer * H2; b2 += wlayer * H;

    int nA = n0 + c; if (nA >= Nn) nA = Nn - 1;
    bf16x8 a0 = *(const bf16x8*)(Gbf + (size_t)nA * H + gq * 8);
    bf16x8 a1 = *(const bf16x8*)(Gbf + (size_t)nA * H + 32 + gq * 8);

    f32x4 acc[8];
    #pragma unroll
    for (int ct = 0; ct < 8; ++ct) {
        f32x4 z = {0.f, 0.f, 0.f, 0.f};
        bf16x8 w0 = *(const bf16x8*)(Wf1 + (size_t)(ct * 64 + lane) * 8);
        bf16x8 w1 = *(const bf16x8*)(Wf1 + (size_t)((8 + ct) * 64 + lane) * 8);
        z = __builtin_amdgcn_mfma_f32_16x16x32_bf16(a0, w0, z, 0, 0, 0);
        z = __builtin_amdgcn_mfma_f32_16x16x32_bf16(a1, w1, z, 0, 0, 0);
        acc[ct] = z;
    }

    float v[8][4];
    #pragma unroll
    for (int ct = 0; ct < 8; ++ct) {
        float bias = b1[ct * 16 + c];
        #pragma unroll
        for (int r = 0; r < 4; ++r) v[ct][r] = acc[ct][r] + bias;
    }
    float mean[4], inv[4];
    #pragma unroll
    for (int r = 0; r < 4; ++r) {
        float s = 0.f;
        #pragma unroll
        for (int ct = 0; ct < 8; ++ct) s += v[ct][r];
        #pragma unroll
        for (int o = 1; o < 16; o <<= 1) s += __shfl_xor(s, o, 64);
        mean[r] = s * (1.f / H2);
    }
    #pragma unroll
    for (int r = 0; r < 4; ++r) {
        float s = 0.f;
        #pragma unroll
        for (int ct = 0; ct < 8; ++ct) { float d = v[ct][r] - mean[r]; s = fmaf(d, d, s); }
        #pragma unroll
        for (int o = 1; o < 16; o <<= 1) s += __shfl_xor(s, o, 64);
        inv[r] = rsqrtf(s * (1.f / H2) + LN_EPS);
    }
    unsigned short* Y = yt[wid];
    #pragma unroll
    for (int ct = 0; ct < 8; ++ct) {
        float gg = g[ct * 16 + c], bb = beta[ct * 16 + c];
        #pragma unroll
        for (int r = 0; r < 4; ++r) {
            float yv = fmaxf(fmaf((v[ct][r] - mean[r]) * inv[r], gg, bb), 0.f);
            Y[(gq * 4 + r) * YSTR + ct * 16 + c] = f2bf(yv);
        }
    }

    f32x4 acc2[4];
    #pragma unroll
    for (int t = 0; t < 4; ++t) acc2[t] = (f32x4){0.f, 0.f, 0.f, 0.f};
    #pragma unroll
    for (int kk = 0; kk < 4; ++kk) {
        bf16x8 af = *(const bf16x8*)(Y + c * YSTR + kk * 32 + gq * 8);
        #pragma unroll
        for (int t = 0; t < 4; ++t) {
            bf16x8 wf = *(const bf16x8*)(Wf2 + (size_t)((kk * 4 + t) * 64 + lane) * 8);
            acc2[t] = __builtin_amdgcn_mfma_f32_16x16x32_bf16(af, wf, acc2[t], 0, 0, 0);
        }
    }

    float b2v[4], gg2[4], bb2[4], lw[4][3];
    const float* g64 = ln_g + lnidx * H;
    const float* be64 = ln_b + lnidx * H;
    #pragma unroll
    for (int tt = 0; tt < 4; ++tt) {
        b2v[tt] = b2[tt * 16 + c];
        gg2[tt] = g64[tt * 16 + c];
        bb2[tt] = be64[tt * 16 + c];
    }
    if (mode == 1) {
        #pragma unroll
        for (int tt = 0; tt < 4; ++tt)
            #pragma unroll
            for (int k = 0; k < 3; ++k) lw[tt][k] = lin_W[(tt * 16 + c) * 3 + k];
    }
    float kmsg = (mode == 0) ? (LOG2E * tptr[lnidx]) : 0.f;

    #pragma unroll
    for (int r = 0; r < 4; ++r) {
        int n = n0 + gq * 4 + r;
        int nc = (n < Nn) ? n : (Nn - 1);
        float hv[4];
        #pragma unroll
        for (int tt = 0; tt < 4; ++tt) hv[tt] = acc2[tt][r] + b2v[tt];
        if (resid) {
            float4 old = *(const float4*)&B[(size_t)nc * H + c * 4];
            hv[0] += old.x; hv[1] += old.y; hv[2] += old.z; hv[3] += old.w;
        }
        float s = hv[0] + hv[1] + hv[2] + hv[3];
        #pragma unroll
        for (int o = 1; o < 16; o <<= 1) s += __shfl_xor(s, o, 64);
        float mu = s * (1.f / H);
        float q = 0.f;
        #pragma unroll
        for (int tt = 0; tt < 4; ++tt) { float d = hv[tt] - mu; q = fmaf(d, d, q); }
        #pragma unroll
        for (int o = 1; o < 16; o <<= 1) q += __shfl_xor(q, o, 64);
        float iv = rsqrtf(q * (1.f / H) + LN_EPS);
        float z[4];
        #pragma unroll
        for (int tt = 0; tt < 4; ++tt)
            z[tt] = fmaxf(fmaf((hv[tt] - mu) * iv, gg2[tt], bb2[tt]), 0.f);

        if (mode == 0) {
            if (n < Nn) {
                float4 hq = {hv[0], hv[1], hv[2], hv[3]};
                *(float4*)&B[(size_t)n * H + c * 4] = hq;
                uint2 zm;
                zm.x = (unsigned int)f2bf(z[0] * kmsg) | ((unsigned int)f2bf(z[1] * kmsg) << 16);
                zm.y = (unsigned int)f2bf(z[2] * kmsg) | ((unsigned int)f2bf(z[3] * kmsg) << 16);
                *(uint2*)&Zmsg[(size_t)n * H + c * 4] = zm;
            }
        } else {
            float p0 = 0.f, p1 = 0.f, p2 = 0.f;
            #pragma unroll
            for (int tt = 0; tt < 4; ++tt) {
                p0 = fmaf(z[tt], lw[tt][0], p0);
                p1 = fmaf(z[tt], lw[tt][1], p1);
                p2 = fmaf(z[tt], lw[tt][2], p2);
            }
            #pragma unroll
            for (int o = 1; o < 16; o <<= 1) {
                p0 += __shfl_xor(p0, o, 64);
                p1 += __shfl_xor(p1, o, 64);
                p2 += __shfl_xor(p2, o, 64);
            }
            if (c == 0 && n < Nn) {
                outp[(size_t)n * 3 + 0] = p0 + lin_b[0];
                outp[(size_t)n * 3 + 1] = p1 + lin_b[1];
                outp[(size_t)n * 3 + 2] = p2 + lin_b[2];
            }
        }
    }
}

extern "C" void kernel_launch(void* const* d_in, const int* in_sizes, int n_in,
                              void* d_out, int out_size, void* d_ws, size_t ws_size,
                              hipStream_t stream) {
    const float* x        = (const float*)d_in[0];
    const int*   eidx     = (const int*)  d_in[1];
    const float* enc_W    = (const float*)d_in[2];
    const float* enc_b    = (const float*)d_in[3];
    const float* t        = (const float*)d_in[4];
    const float* mlp_W1   = (const float*)d_in[5];
    const float* mlp_b1   = (const float*)d_in[6];
    const float* mlp_g    = (const float*)d_in[7];
    const float* mlp_beta = (const float*)d_in[8];
    const float* mlp_W2   = (const float*)d_in[9];
    const float* mlp_b2   = (const float*)d_in[10];
    const float* ln_g     = (const float*)d_in[11];
    const float* ln_b     = (const float*)d_in[12];
    const float* lin_W    = (const float*)d_in[13];
    const float* lin_b    = (const float*)d_in[14];
    float* out = (float*)d_out;

    const int N = in_sizes[0] / 3;
    const int E = in_sizes[1] / 2;
    const int* src = eidx;
    const int* dst = eidx + E;
    const int nbuck = (N + 255) >> 8;

    // workspace layout (~78 MB peak; bdata aliases Gbf — consumed by bsort before gather)
    float* Bm = (float*)d_ws;                          // N*64 f32
    int2* rowq = (int2*)(Bm + (size_t)N * H);          // 512*256 int2
    int* bcnt      = (int*)(rowq + 512 * 256);         // 512
    int* srcs_sorted = bcnt + 512;                     // 512*OSTRIDE
    unsigned short* Zself = (unsigned short*)(srcs_sorted + 512 * OSTRIDE); // N*64
    unsigned short* Zmsg  = Zself + (size_t)N * H;                // (N+1)*64
    unsigned short* Gbf   = Zmsg + (size_t)(N + 1) * H;           // N*64
    unsigned short* Wf1   = Gbf + (size_t)N * H;                  // 3*8192
    unsigned short* Wf2   = Wf1 + 3 * 8192;                       // 3*8192
    unsigned int* bdata = (unsigned int*)Gbf;          // 512*BSTRIDE u32 (9.4MB <= 12.8MB)

    const int eBlocks = (E + CHUNK - 1) / CHUNK;

    hipMemsetAsync(bcnt, 0, 512 * sizeof(int), stream);
    bscat_k<<<eBlocks, 256, 0, stream>>>(src, dst, bcnt, bdata, E, nbuck);
    bsort_k<<<nbuck, 256, 0, stream>>>(bdata, bcnt, rowq, srcs_sorted, N);

    wprep_k<<<192, 256, 0, stream>>>(mlp_W1, mlp_W2, Wf1, Wf2);
    encoder_k<<<((size_t)(N + 1) * H + 255) / 256, 256, 0, stream>>>(x, enc_W, enc_b, Zself, Zmsg, t, N);

    const int gBlocks   = (N + 15) / 16;    // gather: 4 nodes/wave, 4 waves/block
    const int mlpBlocks = (N + 63) / 64;    // mlp: 16 nodes/wave

    gather_k<<<gBlocks, 256, 0, stream>>>(Zmsg, Zself, Gbf, rowq, srcs_sorted, t, 0, N);
    mlp_k<<<mlpBlocks, 256, 0, stream>>>(Gbf, Bm, Wf1, Wf2, mlp_b1, mlp_g, mlp_beta, mlp_b2,
                                         Zmsg, t, ln_g, ln_b, lin_W, lin_b, out,
                                         0, 1, 0, 0, N);
    gather_k<<<gBlocks, 256, 0, stream>>>(Zmsg, Zself, Gbf, rowq, srcs_sorted, t, 1, N);
    mlp_k<<<mlpBlocks, 256, 0, stream>>>(Gbf, Bm, Wf1, Wf2, mlp_b1, mlp_g, mlp_beta, mlp_b2,
                                         Zmsg, t, ln_g, ln_b, lin_W, lin_b, out,
                                         1, 2, 1, 0, N);
    gather_k<<<gBlocks, 256, 0, stream>>>(Zmsg, Zself, Gbf, rowq, srcs_sorted, t, 2, N);
    mlp_k<<<mlpBlocks, 256, 0, stream>>>(Gbf, Bm, Wf1, Wf2, mlp_b1, mlp_g, mlp_beta, mlp_b2,
                                         Zmsg, t, ln_g, ln_b, lin_W, lin_b, out,
                                         2, 0, 1, 1, N);
}